// Round 2
// baseline (1838.330 us; speedup 1.0000x reference)
//
#include <hip/hip_runtime.h>
#include <hip/hip_bf16.h>
#include <stdint.h>

typedef __attribute__((ext_vector_type(8))) short bf16x8;
typedef __attribute__((ext_vector_type(4))) float f32x4;

__device__ __forceinline__ float bf2f(unsigned short u){
  union { unsigned int i; float f; } v; v.i = ((unsigned int)u) << 16; return v.f;
}
__device__ __forceinline__ unsigned short f2bf(float f){
  union { float f; unsigned int i; } v; v.f = f;
  return (unsigned short)((v.i + 0x7FFFu + ((v.i >> 16) & 1u)) >> 16);
}

__device__ __forceinline__ void gload16(const void* g, void* l){
  __builtin_amdgcn_global_load_lds(
      (const __attribute__((address_space(1))) void*)g,
      (__attribute__((address_space(3))) void*)l, 16, 0, 0);
}

// ---------------- weight cast + transpose: W[K][N] f32 -> Wt[N][K] bf16 ----------------
__global__ __launch_bounds__(256) void k_castT(const float* __restrict__ W,
                                               unsigned short* __restrict__ Wt,
                                               int K, int N){
  __shared__ float tl[32][33];
  int ntn = N >> 5;
  int kt = blockIdx.x / ntn, nt = blockIdx.x % ntn;
  int r = threadIdx.x >> 5, c = threadIdx.x & 31;
#pragma unroll
  for (int rr = 0; rr < 4; rr++){
    int row = (kt << 5) + r + (rr << 3);
    tl[r + (rr << 3)][c] = W[(long)row * N + (nt << 5) + c];
  }
  __syncthreads();
#pragma unroll
  for (int rr = 0; rr < 4; rr++){
    int n = (nt << 5) + r + (rr << 3);
    int k = (kt << 5) + c;
    Wt[(long)n * K + k] = f2bf(tl[c][r + (rr << 3)]);
  }
}

// ---------------- LayerNorm fp32 -> bf16 ----------------
// mode 1: block p = window-ordered token (200*196); pads -> zero rows.
// mode 0: plain rows.
__global__ __launch_bounds__(256) void k_ln(const float* __restrict__ X,
                                            const float* __restrict__ w,
                                            const float* __restrict__ b,
                                            unsigned short* __restrict__ out,
                                            int mode){
  int p = blockIdx.x, t = threadIdx.x;
  unsigned short* orow = out + (long)p * 768;
  const float* xrow;
  if (mode == 1){
    int win = p / 196, tok = p - win * 196;
    int bb = win / 25, wrem = win - bb * 25;
    int wy = wrem / 5, wx = wrem - wy * 5;
    int ty = tok / 14, tx = tok - ty * 14;
    int yy = wy * 14 + ty, xx = wx * 14 + tx;
    if (yy >= 64 || xx >= 64){
      for (int j = t; j < 768; j += 256) orow[j] = 0;
      return;
    }
    xrow = X + (long)((bb * 64 + yy) * 64 + xx) * 768;
  } else {
    xrow = X + (long)p * 768;
  }
  float v0 = xrow[t], v1 = xrow[t + 256], v2 = xrow[t + 512];
  float s = v0 + v1 + v2, q = v0 * v0 + v1 * v1 + v2 * v2;
#pragma unroll
  for (int off = 32; off; off >>= 1){ s += __shfl_down(s, off); q += __shfl_down(q, off); }
  __shared__ float ps[4], pq[4], mv[2];
  int wid = t >> 6;
  if ((t & 63) == 0){ ps[wid] = s; pq[wid] = q; }
  __syncthreads();
  if (t == 0){
    float S = ps[0] + ps[1] + ps[2] + ps[3];
    float Q = pq[0] + pq[1] + pq[2] + pq[3];
    float mu = S * (1.0f / 768.0f);
    float var = Q * (1.0f / 768.0f) - mu * mu;
    mv[0] = mu; mv[1] = rsqrtf(var + 1e-5f);
  }
  __syncthreads();
  float mu = mv[0], rs = mv[1];
  orow[t]       = f2bf((v0 - mu) * rs * w[t]       + b[t]);
  orow[t + 256] = f2bf((v1 - mu) * rs * w[t + 256] + b[t + 256]);
  orow[t + 512] = f2bf((v2 - mu) * rs * w[t + 512] + b[t + 512]);
}

// ---------------- 128x128 tile GEMM, BK=32, 4 waves ----------------
// C[i][j] = sum_k A[i][k]*Bt[j][k] (+bias). A stride lda, Bt stride ldb.
// MODE 0: -> bf16 [M][N]            MODE 2: GELU -> bf16 [M][N]
// MODE 1: window->spatial scatter, + addsrc -> of32
// MODE 3: of32[idx] = v + addsrc[idx] (bias may be null)
template<int MODE>
__global__ __launch_bounds__(256) void k_gemm(const unsigned short* __restrict__ A,
                                              const unsigned short* __restrict__ Bt,
                                              const float* bias,
                                              unsigned short* obf,
                                              float* of32,
                                              const float* addsrc,
                                              int M, int N, int K, int lda, int ldb,
                                              int tilesN){
  __shared__ __align__(16) unsigned short lA[128 * 32];
  __shared__ __align__(16) unsigned short lB[128 * 32];
  int t = threadIdx.x;
  int tm = blockIdx.x / tilesN, tn = blockIdx.x % tilesN;

  int sl = (t & 3) ^ ((t >> 3) & 3);           // logical k-chunk this thread fetches
  const unsigned short* ga[2]; const unsigned short* gb[2];
#pragma unroll
  for (int c2 = 0; c2 < 2; c2++){
    int i = tm * 128 + c2 * 64 + (t >> 2); if (i > M - 1) i = M - 1;
    ga[c2] = A + (long)i * lda + sl * 8;
    int n = tn * 128 + c2 * 64 + (t >> 2);
    gb[c2] = Bt + (long)n * ldb + sl * 8;
  }
  unsigned short* la = lA + t * 8;
  unsigned short* lb = lB + t * 8;

  int lm = t & 15, lg = (t & 63) >> 4, wv = t >> 6;
  int wr = wv >> 1, wc = wv & 1;
  int laneoff = lm * 32 + ((lg ^ ((lm >> 1) & 3)) * 8);

  f32x4 acc[4][4];
#pragma unroll
  for (int a1 = 0; a1 < 4; a1++)
#pragma unroll
    for (int b1 = 0; b1 < 4; b1++) acc[a1][b1] = (f32x4){0.f, 0.f, 0.f, 0.f};

  for (int k0 = 0; k0 < K; k0 += 32){
    __syncthreads();
    gload16(ga[0] + k0, la);
    gload16(ga[1] + k0, la + 2048);
    gload16(gb[0] + k0, lb);
    gload16(gb[1] + k0, lb + 2048);
    __syncthreads();
    bf16x8 af[4], bfr[4];
#pragma unroll
    for (int mi = 0; mi < 4; mi++)
      af[mi] = *(const bf16x8*)(lA + (wr * 64 + mi * 16) * 32 + laneoff);
#pragma unroll
    for (int ni = 0; ni < 4; ni++)
      bfr[ni] = *(const bf16x8*)(lB + (wc * 64 + ni * 16) * 32 + laneoff);
#pragma unroll
    for (int mi = 0; mi < 4; mi++)
#pragma unroll
      for (int ni = 0; ni < 4; ni++)
        acc[mi][ni] = __builtin_amdgcn_mfma_f32_16x16x32_bf16(af[mi], bfr[ni], acc[mi][ni], 0, 0, 0);
  }

  int i0 = tm * 128 + wr * 64, j0 = tn * 128 + wc * 64;
#pragma unroll
  for (int mi = 0; mi < 4; mi++){
#pragma unroll
    for (int ni = 0; ni < 4; ni++){
      int jc = j0 + ni * 16 + lm;
      float bv = bias ? bias[jc] : 0.0f;
#pragma unroll
      for (int r = 0; r < 4; r++){
        int ir = i0 + mi * 16 + lg * 4 + r;
        float v = acc[mi][ni][r] + bv;
        if (MODE == 0){
          if (ir < M) obf[(long)ir * N + jc] = f2bf(v);
        } else if (MODE == 1){
          if (ir < M){
            int win = ir / 196, tok = ir - win * 196;
            int bb = win / 25, wrem = win - bb * 25;
            int wy = wrem / 5, wx = wrem - wy * 5;
            int yy = wy * 14 + tok / 14, xx = wx * 14 + tok % 14;
            if (yy < 64 && xx < 64){
              long row = (long)((bb * 64 + yy) * 64 + xx);
              of32[row * 768 + jc] = v + addsrc[row * 768 + jc];
            }
          }
        } else if (MODE == 2){
          float g = 0.5f * v * (1.0f + erff(v * 0.70710678118654752f));
          obf[(long)ir * N + jc] = f2bf(g);
        } else {
          long idx = (long)ir * N + jc;
          of32[idx] = v + addsrc[idx];
        }
      }
    }
  }
}

// ---------------- fused window attention: one block per (window, head) ----------------
// qkv layout: [39200][2304] bf16 (row = win*196+tok; cols 0..767 Q, 768.. K, 1536.. V)
// static LDS 64,224 B: Vt[64][208] + P[4][16][208] + rel tables bf16
__global__ __launch_bounds__(256) void k_attn(const unsigned short* __restrict__ qkv,
                                              const float* __restrict__ rph,
                                              const float* __restrict__ rpw,
                                              unsigned short* __restrict__ out){
  __shared__ __align__(16) unsigned short Vt[64 * 208];
  __shared__ __align__(16) unsigned short Pb[4 * 16 * 208];
  __shared__ unsigned short relhb[2744], relwb[2744];

  int t = threadIdx.x;
  int wh = blockIdx.x;
  int win = wh / 12, head = wh - win * 12;
  const unsigned short* qg = qkv + (long)(win * 196) * 2304 + head * 64;
  const unsigned short* kg = qg + 768;
  const unsigned short* vg = qg + 1536;

  // stage V^T (cols k = token, zero-pad k 196..207)
  for (int ch = t; ch < 1568; ch += 256){
    int tok = ch >> 3, c8 = (ch & 7) * 8;
    bf16x8 vv = *(const bf16x8*)(&vg[(long)tok * 2304 + c8]);
#pragma unroll
    for (int j = 0; j < 8; j++) Vt[(c8 + j) * 208 + tok] = (unsigned short)vv[j];
  }
  for (int idx = t; idx < 64 * 12; idx += 256){
    int cc = idx / 12, kc = idx - (idx / 12) * 12;
    Vt[cc * 208 + 196 + kc] = 0;
  }
  // decomposed rel-pos tables (bf16): relh[q][kh] = Q[q,:]·rph[ty-kh+13,:]
  for (int e = t; e < 5488; e += 256){
    int tab = e / 2744, rem = e - tab * 2744;
    int q = rem / 14, kx = rem - (rem / 14) * 14;
    int ty = q / 14, tx = q - ty * 14;
    const float* tp = tab ? (rpw + (tx - kx + 13) * 64) : (rph + (ty - kx + 13) * 64);
    const unsigned short* qrow = qg + (long)q * 2304;
    float acc = 0.f;
#pragma unroll
    for (int c = 0; c < 64; c += 8){
      bf16x8 qv = *(const bf16x8*)(&qrow[c]);
#pragma unroll
      for (int j = 0; j < 8; j++) acc += bf2f((unsigned short)qv[j]) * tp[c + j];
    }
    (tab ? relwb : relhb)[q * 14 + kx] = f2bf(acc);
  }
  __syncthreads();

  int lane = t & 63, wv = t >> 6;
  int lm = lane & 15, lg = lane >> 4;
  unsigned short* Pw = Pb + wv * (16 * 208);

  int kh_[13], kw_[13];
#pragma unroll
  for (int nt = 0; nt < 13; nt++){
    int kc = nt * 16 + lm;
    if (kc < 196){ kh_[nt] = kc / 14; kw_[nt] = kc - kh_[nt] * 14; }
    else { kh_[nt] = -1; kw_[nt] = 0; }
  }

  for (int mt = wv; mt < 13; mt += 4){
    int qr = mt * 16 + lm; if (qr > 195) qr = 195;
    bf16x8 aq0 = *(const bf16x8*)(&qg[(long)qr * 2304 + lg * 8]);
    bf16x8 aq1 = *(const bf16x8*)(&qg[(long)qr * 2304 + 32 + lg * 8]);
    // ---- S = Q K^T ----
    f32x4 sacc[13];
#pragma unroll
    for (int nt = 0; nt < 13; nt++) sacc[nt] = (f32x4){0.f, 0.f, 0.f, 0.f};
#pragma unroll
    for (int nt = 0; nt < 13; nt++){
      int kr = nt * 16 + lm; if (kr > 195) kr = 195;
      bf16x8 bk0 = *(const bf16x8*)(&kg[(long)kr * 2304 + lg * 8]);
      bf16x8 bk1 = *(const bf16x8*)(&kg[(long)kr * 2304 + 32 + lg * 8]);
      sacc[nt] = __builtin_amdgcn_mfma_f32_16x16x32_bf16(aq0, bk0, sacc[nt], 0, 0, 0);
      sacc[nt] = __builtin_amdgcn_mfma_f32_16x16x32_bf16(aq1, bk1, sacc[nt], 0, 0, 0);
    }
    // ---- bias + softmax (row = mt*16+lg*4+r, col = nt*16+lm) ----
    float rinv[4];
#pragma unroll
    for (int r = 0; r < 4; r++){
      int qrow = mt * 16 + lg * 4 + r;
      int qb = (qrow < 196) ? qrow * 14 : 0;
      float sv[13];
      float mx = -1e30f;
#pragma unroll
      for (int nt = 0; nt < 13; nt++){
        float s;
        if (kh_[nt] >= 0)
          s = sacc[nt][r] * 0.125f + bf2f(relhb[qb + kh_[nt]]) + bf2f(relwb[qb + kw_[nt]]);
        else s = -1e30f;
        sv[nt] = s; mx = fmaxf(mx, s);
      }
      mx = fmaxf(mx, __shfl_xor(mx, 1));
      mx = fmaxf(mx, __shfl_xor(mx, 2));
      mx = fmaxf(mx, __shfl_xor(mx, 4));
      mx = fmaxf(mx, __shfl_xor(mx, 8));
      float sum = 0.f;
#pragma unroll
      for (int nt = 0; nt < 13; nt++){
        float p = __expf(sv[nt] - mx);
        sum += p;
        Pw[(lg * 4 + r) * 208 + nt * 16 + lm] = f2bf(p);
      }
      sum += __shfl_xor(sum, 1); sum += __shfl_xor(sum, 2);
      sum += __shfl_xor(sum, 4); sum += __shfl_xor(sum, 8);
      rinv[r] = 1.0f / sum;
    }
    // ---- O = P V : k spans 0..191 full, tail 192..207 via half-zero A-frag ----
    f32x4 oacc[4];
#pragma unroll
    for (int vt = 0; vt < 4; vt++) oacc[vt] = (f32x4){0.f, 0.f, 0.f, 0.f};
#pragma unroll
    for (int kk = 0; kk < 6; kk++){
      bf16x8 ap = *(const bf16x8*)(&Pw[lm * 208 + kk * 32 + lg * 8]);
#pragma unroll
      for (int vt = 0; vt < 4; vt++){
        bf16x8 bv = *(const bf16x8*)(&Vt[(vt * 16 + lm) * 208 + kk * 32 + lg * 8]);
        oacc[vt] = __builtin_amdgcn_mfma_f32_16x16x32_bf16(ap, bv, oacc[vt], 0, 0, 0);
      }
    }
    {
      bf16x8 ap = *(const bf16x8*)(&Pw[lm * 208 + 176 + lg * 8]);
      if (lg < 2) ap = (bf16x8){0, 0, 0, 0, 0, 0, 0, 0};   // k 176..191 already counted
#pragma unroll
      for (int vt = 0; vt < 4; vt++){
        bf16x8 bv = *(const bf16x8*)(&Vt[(vt * 16 + lm) * 208 + 176 + lg * 8]);
        oacc[vt] = __builtin_amdgcn_mfma_f32_16x16x32_bf16(ap, bv, oacc[vt], 0, 0, 0);
      }
    }
#pragma unroll
    for (int vt = 0; vt < 4; vt++){
#pragma unroll
      for (int r = 0; r < 4; r++){
        int orow = mt * 16 + lg * 4 + r;
        if (orow < 196)
          out[(long)(win * 196 + orow) * 768 + head * 64 + vt * 16 + lm] =
              f2bf(oacc[vt][r] * rinv[r]);
      }
    }
  }
}

// ---------------- workspace layout ----------------
// R0 @0         : 60,211,200  hpad -> attout -> h2
// R1 @60211200  : weights (qkvT 3538944 | projT 1179648 | l1T 4718592 | l2T 4718592)
// R2 @74366976  : qkv [39200][2304] bf16 (180,633,600) -> hidden (full 201,326,592 / chunk 100,663,296)
static const long O_W    = 60211200;
static const long O_R2   = 74366976;
static const unsigned long WS_FULL  = 275693568UL;  // R2 holds full hidden [32768][3072] bf16

extern "C" void kernel_launch(void* const* d_in, const int* in_sizes, int n_in,
                              void* d_out, int out_size, void* d_ws, size_t ws_size,
                              hipStream_t stream){
  const float* x     = (const float*)d_in[0];
  const float* n1w   = (const float*)d_in[1];
  const float* n1b   = (const float*)d_in[2];
  const float* qkvw  = (const float*)d_in[3];
  const float* qkvb  = (const float*)d_in[4];
  const float* projw = (const float*)d_in[5];
  const float* projb = (const float*)d_in[6];
  const float* rph   = (const float*)d_in[7];
  const float* rpw   = (const float*)d_in[8];
  const float* n2w   = (const float*)d_in[9];
  const float* n2b   = (const float*)d_in[10];
  const float* l1w   = (const float*)d_in[11];
  const float* l1b   = (const float*)d_in[12];
  const float* l2w   = (const float*)d_in[13];
  const float* l2b   = (const float*)d_in[14];
  float* out = (float*)d_out;
  char* ws = (char*)d_ws;

  unsigned short* hpad   = (unsigned short*)(ws);            // R0
  unsigned short* attout = (unsigned short*)(ws);            // R0 (hpad dead)
  unsigned short* h2     = (unsigned short*)(ws);            // R0 (attout dead)
  unsigned short* wqkvT  = (unsigned short*)(ws + O_W);
  unsigned short* wprojT = (unsigned short*)(ws + O_W + 3538944);
  unsigned short* wl1T   = (unsigned short*)(ws + O_W + 3538944 + 1179648);
  unsigned short* wl2T   = (unsigned short*)(ws + O_W + 3538944 + 1179648 + 4718592);
  unsigned short* qkvbuf = (unsigned short*)(ws + O_R2);
  unsigned short* hidden = (unsigned short*)(ws + O_R2);     // reuse after attention

  const bool full = (ws_size >= WS_FULL);

  // weight casts
  k_castT<<<(768 / 32) * (2304 / 32), 256, 0, stream>>>(qkvw, wqkvT, 768, 2304);
  k_castT<<<(768 / 32) * (768 / 32),  256, 0, stream>>>(projw, wprojT, 768, 768);
  k_castT<<<(768 / 32) * (3072 / 32), 256, 0, stream>>>(l1w, wl1T, 768, 3072);
  k_castT<<<(3072 / 32) * (768 / 32), 256, 0, stream>>>(l2w, wl2T, 3072, 768);

  // LN1 -> window-ordered padded bf16 [39200][768]
  k_ln<<<39200, 256, 0, stream>>>(x, n1w, n1b, hpad, 1);

  // QKV GEMM: [39200][768] x [2304][768]^T -> bf16 [39200][2304]
  k_gemm<0><<<307 * 18, 256, 0, stream>>>(hpad, wqkvT, qkvb, qkvbuf, nullptr, nullptr,
                                          39200, 2304, 768, 768, 768, 18);

  // fused window attention -> attout bf16 [39200][768]
  k_attn<<<2400, 256, 0, stream>>>(qkvbuf, rph, rpw, attout);

  // proj + unpartition + residual -> y in d_out (fp32)
  k_gemm<1><<<307 * 6, 256, 0, stream>>>(attout, wprojT, projb, nullptr, out, x,
                                         39200, 768, 768, 768, 768, 6);

  // LN2 (reads y from d_out) -> h2 bf16 [32768][768]
  k_ln<<<32768, 256, 0, stream>>>(out, n2w, n2b, h2, 0);

  if (full){
    // lin1 + GELU -> hidden bf16 [32768][3072]
    k_gemm<2><<<256 * 24, 256, 0, stream>>>(h2, wl1T, l1b, hidden, nullptr, nullptr,
                                            32768, 3072, 768, 768, 768, 24);
    // lin2 + residual (in-place on d_out)
    k_gemm<3><<<256 * 6, 256, 0, stream>>>(hidden, wl2T, l2b, nullptr, out, out,
                                           32768, 768, 3072, 3072, 3072, 6);
  } else {
    // 2-chunk MLP: hidden chunk [32768][1536] fits inside qkv footprint
    for (int c = 0; c < 2; c++){
      k_gemm<2><<<256 * 12, 256, 0, stream>>>(h2, wl1T + (long)c * 1536 * 768,
                                              l1b + c * 1536, hidden, nullptr, nullptr,
                                              32768, 1536, 768, 768, 768, 12);
      k_gemm<3><<<256 * 6, 256, 0, stream>>>(hidden, wl2T + c * 1536,
                                             c == 0 ? l2b : nullptr, nullptr, out, out,
                                             32768, 768, 1536, 1536, 3072, 6);
    }
  }
}